// Round 1
// baseline (963.607 us; speedup 1.0000x reference)
//
#include <hip/hip_runtime.h>
#include <stdint.h>

typedef unsigned long long u64;
typedef unsigned int u32;

#define NVERT 300000
#define NTET  1200000
#define NE    (NTET*6)              // 7,200,000 edges
#define TILE  4096
#define NTILES ((NE + TILE - 1)/TILE)   // 1758
#define IDXBITS 23
#define IDXMASK ((1u<<IDXBITS)-1)

// output layout (float32 elements)
#define VERTS_OFF 0
#define FACES_OFF 21600000
#define NUMT_OFF  28800000
#define CROSS_OFF 30000000

__constant__ int c_ea[6] = {0,0,0,1,1,2};
__constant__ int c_eb[6] = {1,2,3,2,3,3};
__constant__ int c_numtri[16] = {0,1,1,2,1,2,2,1,1,2,2,1,2,1,1,0};
__constant__ int c_tritab[16][6] = {
 {-1,-1,-1,-1,-1,-1},{1,0,2,-1,-1,-1},{4,0,3,-1,-1,-1},{1,4,2,1,3,4},
 {3,1,5,-1,-1,-1},{2,3,0,2,5,3},{1,4,0,1,5,4},{4,2,5,-1,-1,-1},
 {4,5,2,-1,-1,-1},{4,1,0,4,5,1},{3,2,0,3,5,2},{1,3,5,-1,-1,-1},
 {4,1,2,4,3,1},{3,0,4,-1,-1,-1},{2,0,1,-1,-1,-1},{-1,-1,-1,-1,-1,-1}};

// LDS swizzle for u64 keys[4096]: spread stride-16 accesses across bank pairs
__device__ __forceinline__ int sw(int j){ return j ^ ((j >> 4) & 15); }

__global__ void k_pack(const int* __restrict__ tet, u64* __restrict__ dst){
  int i = blockIdx.x*blockDim.x + threadIdx.x;
  if (i >= NE) return;
  int t = i/6, k = i - t*6;
  int a = tet[t*4 + c_ea[k]];
  int b = tet[t*4 + c_eb[k]];
  int e0 = min(a,b), e1 = max(a,b);
  u64 code = (u64)e0 * NVERT + (u64)e1;
  dst[i] = (code << IDXBITS) | (u64)i;
}

__global__ void k_hist(const u64* __restrict__ src, u32* __restrict__ hist, int shift){
  __shared__ u32 h[256];
  int tid = threadIdx.x;
  h[tid] = 0; __syncthreads();
  int base = blockIdx.x * TILE;
  for (int k=0;k<16;k++){
    int i = base + k*256 + tid;
    if (i < NE){
      u32 d = (u32)((src[i] >> shift) & 255);
      atomicAdd(&h[d], 1u);
    }
  }
  __syncthreads();
  hist[tid * NTILES + blockIdx.x] = h[tid];
}

// per-digit exclusive scan across tiles (in place), digit totals out
__global__ void k_scan_digit(u32* __restrict__ hist, u32* __restrict__ digitTot){
  __shared__ u32 s[256];
  int d = blockIdx.x, tid = threadIdx.x;
  u32* row = hist + (size_t)d * NTILES;
  u32 carry = 0;
  for (int start=0; start<NTILES; start+=256){
    int idx = start + tid;
    u32 x = (idx < NTILES) ? row[idx] : 0;
    s[tid] = x; __syncthreads();
    for (int off=1; off<256; off<<=1){
      u32 t = (tid >= off) ? s[tid-off] : 0;
      __syncthreads();
      s[tid] += t;
      __syncthreads();
    }
    u32 incl = s[tid];
    u32 tot  = s[255];
    if (idx < NTILES) row[idx] = carry + incl - x;
    carry += tot;
    __syncthreads();
  }
  if (tid==0) digitTot[d] = carry;
}

__global__ void k_scan_base(const u32* __restrict__ digitTot, u32* __restrict__ digitOff){
  __shared__ u32 s[256];
  int tid = threadIdx.x;
  u32 x = digitTot[tid];
  s[tid]=x; __syncthreads();
  for (int off=1; off<256; off<<=1){
    u32 t=(tid>=off)?s[tid-off]:0;
    __syncthreads();
    s[tid]+=t;
    __syncthreads();
  }
  digitOff[tid] = s[tid]-x;
}

__global__ __launch_bounds__(256) void k_scatter(const u64* __restrict__ src, u64* __restrict__ dst,
      const u32* __restrict__ hist, const u32* __restrict__ digitOff, int shift){
  __shared__ u64 keys[TILE];
  __shared__ u32 sc[256];
  __shared__ u32 lstart[256];
  int tid = threadIdx.x;
  int base = blockIdx.x * TILE;
  for (int k=0;k<16;k++){
    int j = k*256 + tid;
    int i = base + j;
    keys[sw(j)] = (i < NE) ? src[i] : ~0ull;
  }
  __syncthreads();
  // 8 stable 1-bit splits -> tile sorted by this pass's digit
  for (int q=0;q<8;q++){
    int sh = shift + q;
    u64 myk[16];
    u32 ones = 0, mask = 0;
    #pragma unroll
    for (int k=0;k<16;k++){
      myk[k] = keys[sw(tid*16+k)];
      u32 b = (u32)((myk[k] >> sh) & 1);
      mask |= b << k;
      ones += b;
    }
    sc[tid] = ones; __syncthreads();
    for (int off=1; off<256; off<<=1){
      u32 t=(tid>=off)?sc[tid-off]:0;
      __syncthreads();
      sc[tid]+=t;
      __syncthreads();
    }
    u32 incl = sc[tid];
    u32 totalOnes = sc[255];
    __syncthreads();
    u32 onesBefore = incl - ones;
    u32 zerosBefore = (u32)(tid*16) - onesBefore;
    u32 Z = TILE - totalOnes;
    #pragma unroll
    for (int k=0;k<16;k++){
      u32 pos;
      if ((mask>>k)&1u){ pos = Z + onesBefore; onesBefore++; }
      else { pos = zerosBefore; zerosBefore++; }
      keys[sw((int)pos)] = myk[k];
    }
    __syncthreads();
  }
  // local run starts per digit
  for (int k=0;k<16;k++){
    int j = k*256+tid;
    u32 d = (u32)((keys[sw(j)] >> shift) & 255);
    bool headj = (j==0) || (((keys[sw(j-1)] >> shift) & 255) != d);
    if (headj) lstart[d] = (u32)j;
  }
  __syncthreads();
  for (int k=0;k<16;k++){
    int j = k*256+tid;
    u64 key = keys[sw(j)];
    if (key == ~0ull) continue;  // padding
    u32 d = (u32)((key >> shift) & 255);
    u32 gpos = digitOff[d] + hist[(size_t)d*NTILES + blockIdx.x] + (u32)j - lstart[d];
    dst[gpos] = key;
  }
}

// per-tile sums of (head, head&cross) over sorted array
__global__ void k_flag_tilesum(const u64* __restrict__ A, const float* __restrict__ sdf,
                               u64* __restrict__ tileSums){
  __shared__ u64 s[256];
  int tid = threadIdx.x;
  int base = blockIdx.x*TILE;
  u32 th=0, tc=0;
  for (int k=0;k<16;k++){
    int i = base + k*256 + tid;
    if (i < NE){
      u64 v = A[i];
      u64 code = v >> IDXBITS;
      bool head = (i==0) || ((A[i-1] >> IDXBITS) != code);
      if (head){
        u32 u0 = (u32)(code / NVERT), u1 = (u32)(code % NVERT);
        bool cross = (sdf[u0] > 0.f) != (sdf[u1] > 0.f);
        th++; if (cross) tc++;
      }
    }
  }
  s[tid] = ((u64)th<<32) | (u64)tc;
  __syncthreads();
  for (int off=128; off>0; off>>=1){
    if (tid<off) s[tid]+=s[tid+off];
    __syncthreads();
  }
  if (tid==0) tileSums[blockIdx.x] = s[0];
}

__global__ void k_scan_tiles(u64* __restrict__ tileSums, u64* __restrict__ tileOff){
  __shared__ u64 s[256];
  int tid = threadIdx.x;
  u64 carry=0;
  for (int start=0; start<NTILES; start+=256){
    int idx=start+tid;
    u64 x = (idx<NTILES)? tileSums[idx] : 0;
    s[tid]=x; __syncthreads();
    for (int off=1;off<256;off<<=1){
      u64 t=(tid>=off)?s[tid-off]:0;
      __syncthreads();
      s[tid]+=t;
      __syncthreads();
    }
    u64 incl=s[tid], tot=s[255];
    if (idx<NTILES) tileOff[idx] = carry + incl - x;
    carry += tot;
    __syncthreads();
  }
}

__global__ __launch_bounds__(256) void k_emit(const u64* __restrict__ A, const float* __restrict__ sdf,
     const float* __restrict__ pos, const u64* __restrict__ tileOff,
     float* __restrict__ verts, float* __restrict__ crossing_out, float* __restrict__ edgeMapF){
  __shared__ u64 s[256];
  int tid=threadIdx.x;
  int base = blockIdx.x*TILE;
  int start = base + tid*16;
  u64 myk[16];
  u32 headm=0, crossm=0;
  #pragma unroll
  for (int k=0;k<16;k++){
    int i = start + k;
    u64 v = 0;
    if (i<NE){
      v = A[i];
      u64 code = v>>IDXBITS;
      bool head = (i==0) || ((A[i-1]>>IDXBITS) != code);
      u32 u0=(u32)(code/NVERT), u1=(u32)(code%NVERT);
      bool cross = (sdf[u0]>0.f) != (sdf[u1]>0.f);
      if (head) headm |= 1u<<k;
      if (cross) crossm |= 1u<<k;
    }
    myk[k]=v;
  }
  u32 th = __popc(headm), tc = __popc(headm & crossm);
  u64 x = ((u64)th<<32)|(u64)tc;
  s[tid]=x; __syncthreads();
  for (int off=1;off<256;off<<=1){
    u64 t=(tid>=off)?s[tid-off]:0;
    __syncthreads();
    s[tid]+=t;
    __syncthreads();
  }
  u64 excl = s[tid]-x;
  u64 baseOff = tileOff[blockIdx.x] + excl;
  u32 H = (u32)(baseOff>>32), C=(u32)(baseOff & 0xFFFFFFFFull);
  for (int k=0;k<16;k++){
    int i = start+k;
    if (i>=NE) break;
    u64 v = myk[k];
    u64 code = v>>IDXBITS;
    u32 orig = (u32)(v & IDXMASK);
    bool head = (headm>>k)&1u;
    bool cross = (crossm>>k)&1u;
    if (head){ H++; if(cross) C++; }
    int m = cross ? (int)C-1 : -1;
    edgeMapF[orig] = (float)m;
    if (head){
      crossing_out[H-1] = cross ? 1.f : 0.f;
      if (cross){
        u32 u0=(u32)(code/NVERT), u1=(u32)(code%NVERT);
        float s0=sdf[u0], s1=sdf[u1];
        float denom = s0-s1;
        float w0 = (-s1)/denom, w1 = s0/denom;
        verts[3*m+0] = pos[u0*3+0]*w0 + pos[u1*3+0]*w1;
        verts[3*m+1] = pos[u0*3+1]*w0 + pos[u1*3+1]*w1;
        verts[3*m+2] = pos[u0*3+2]*w0 + pos[u1*3+2]*w1;
      }
    }
  }
}

__global__ void k_faces(const int* __restrict__ tet, const float* __restrict__ sdf,
                        float* faceRegion, float* __restrict__ numt){
  int t = blockIdx.x*blockDim.x + threadIdx.x;
  if (t>=NTET) return;
  int occ=0;
  #pragma unroll
  for (int j=0;j<4;j++){ int v=tet[t*4+j]; if (sdf[v]>0.f) occ |= 1<<j; }
  int ntri = c_numtri[occ];
  float em[6];
  #pragma unroll
  for (int j=0;j<6;j++) em[j] = faceRegion[t*6+j];   // edge mapping written by k_emit
  float f[6];
  #pragma unroll
  for (int j=0;j<6;j++){
    int tri = c_tritab[occ][j];
    f[j] = ((j/3) < ntri) ? em[tri] : -1.f;
  }
  #pragma unroll
  for (int j=0;j<6;j++) faceRegion[t*6+j] = f[j];
  numt[t] = (float)ntri;
}

extern "C" void kernel_launch(void* const* d_in, const int* in_sizes, int n_in,
                              void* d_out, int out_size, void* d_ws, size_t ws_size,
                              hipStream_t stream) {
  const float* pos = (const float*)d_in[0];
  const float* sdf = (const float*)d_in[1];
  const int*   tet = (const int*)d_in[2];
  float* out = (float*)d_out;

  // ws layout
  u64* bufA     = (u64*)d_ws;                                        // 57,600,000 B
  u32* hist     = (u32*)((char*)d_ws + 57600000);                    // 1,800,192 B
  u32* digitTot = (u32*)((char*)d_ws + 57600000 + 1800192);          // 1024 B
  u32* digitOff = digitTot + 256;                                    // 1024 B
  u64* tileSums = (u64*)((char*)d_ws + 57600000 + 1800192 + 2048);
  u64* tileOff  = tileSums + NTILES;
  // d_out's first 57.6MB doubles as sort buffer B (rewritten afterwards)
  u64* bufB = (u64*)d_out;

  k_pack<<<(NE+255)/256, 256, 0, stream>>>(tet, bufB);

  u64 *src = bufB, *dst = bufA;
  for (int p=0; p<5; p++){
    int shift = IDXBITS + 8*p;
    k_hist<<<NTILES, 256, 0, stream>>>(src, hist, shift);
    k_scan_digit<<<256, 256, 0, stream>>>(hist, digitTot);
    k_scan_base<<<1, 256, 0, stream>>>(digitTot, digitOff);
    k_scatter<<<NTILES, 256, 0, stream>>>(src, dst, hist, digitOff, shift);
    u64* tmp = src; src = dst; dst = tmp;
  }
  // after 5 passes the sorted array lives in bufA (== src)

  hipMemsetAsync(out + VERTS_OFF, 0, (size_t)21600000*4, stream);  // verts
  hipMemsetAsync(out + CROSS_OFF, 0, (size_t)7200000*4, stream);   // crossing

  k_flag_tilesum<<<NTILES, 256, 0, stream>>>(bufA, sdf, tileSums);
  k_scan_tiles<<<1, 256, 0, stream>>>(tileSums, tileOff);
  k_emit<<<NTILES, 256, 0, stream>>>(bufA, sdf, pos, tileOff,
                                     out + VERTS_OFF, out + CROSS_OFF, out + FACES_OFF);
  k_faces<<<(NTET+255)/256, 256, 0, stream>>>(tet, sdf, out + FACES_OFF, out + NUMT_OFF);
}